// Round 9
// baseline (11137.643 us; speedup 1.0000x reference)
//
#include <hip/hip_runtime.h>
#include <math.h>

// Speller round 16: mega-block — LSTM tail chased inside attn's poll shadow.
//   v15 confirmed the serial floor (~4.0ms): attn 16.3us/step has ~10us of
//   IF$ RTT poll idle; the 1.7ms lstm tail fits in that shadow. One
//   1024-thread block/CU: waves 0-7 attn (v13-verbatim protocol), waves
//   8-11 lstm1 (lag 2), waves 12-15 lstm2 (lag 4). Chaser W/R GEMVs stream
//   pre-transposed weights (4-lane broadcast per col, 256KB/WG/step) INSIDE
//   the two attn flag-poll windows. Lockstep barrier schedule: attn's BAR3
//   chain proves iter t-1 cohort-complete at iter t -> lag-2 chaser inputs
//   (sc1-published, virgin-line reads) ready with zero spin, no deadlock.
//   4 drain iters (cohort bar on FLG_1) + folded decoder.

#define U_   512
#define S_   512
#define T_   128
#define B_   32
#define G4   2048
#define V_   46
#define FSTR 32            // flag stride in u32 = 128 B

#define AT_LD(p)     __hip_atomic_load((p), __ATOMIC_RELAXED, __HIP_MEMORY_SCOPE_AGENT)
#define AT_ST(p, v)  __hip_atomic_store((p), (v), __ATOMIC_RELAXED, __HIP_MEMORY_SCOPE_AGENT)

// ---------------- GEMM: Z[M,2048] = A[M,512] @ W[512,2048] + b ----------------
__global__ __launch_bounds__(256) void gemm_k512(
    const float* __restrict__ A, const float* __restrict__ W,
    const float* __restrict__ b, float* __restrict__ Z) {
  const int tid = threadIdx.x;
  const int j = blockIdx.x * 1024 + tid * 4;
  const int i0 = blockIdx.y * 8;
  float4 bj = *(const float4*)(b + j);
  float4 acc[8];
#pragma unroll
  for (int r = 0; r < 8; ++r) acc[r] = bj;
  const float* Arow = A + (size_t)i0 * U_;
  for (int k = 0; k < U_; ++k) {
    float4 w = *(const float4*)(W + (size_t)k * G4 + j);
#pragma unroll
    for (int r = 0; r < 8; ++r) {
      float a = Arow[(size_t)r * U_ + k];
      acc[r].x = fmaf(a, w.x, acc[r].x);
      acc[r].y = fmaf(a, w.y, acc[r].y);
      acc[r].z = fmaf(a, w.z, acc[r].z);
      acc[r].w = fmaf(a, w.w, acc[r].w);
    }
  }
#pragma unroll
  for (int r = 0; r < 8; ++r)
    *(float4*)(Z + (size_t)(i0 + r) * G4 + j) = acc[r];
}

// ---------------- transpose M[512][2048] -> MT[2048][512] ----------------
__global__ __launch_bounds__(256) void transpose_R(
    const float* __restrict__ R, float* __restrict__ RT) {
  __shared__ float tile[64][65];
  const int c0 = blockIdx.x * 64, k0 = blockIdx.y * 64;
  const int tc = threadIdx.x & 63, tr = threadIdx.x >> 6;
  for (int r = tr; r < 64; r += 4)
    tile[r][tc] = R[(size_t)(k0 + r) * G4 + c0 + tc];
  __syncthreads();
  for (int r = tr; r < 64; r += 4)
    RT[(size_t)(c0 + r) * 512 + k0 + tc] = tile[tc][r];
}

// ---------------- mega: attn + chased lstm1/lstm2 + decoder ----------------
// 256 blocks x 1024 threads. dyn LDS 141376 B + ~4.6KB static -> 1 blk/CU.
// waves 0-7: attn (8 cohorts x 32 blocks, 4 batches) — v13 protocol verbatim.
// waves 8-11: lstm1, processes s1 = t-2. waves 12-15: lstm2, s2 = t-4.
__global__ __launch_bounds__(1024) void mega(
    const float* __restrict__ x, const float* __restrict__ ZY,
    const float* __restrict__ RT,
    const float* __restrict__ W1T, const float* __restrict__ R1T,
    const float* __restrict__ b1,
    const float* __restrict__ W2T, const float* __restrict__ R2T,
    const float* __restrict__ b2,
    const float* __restrict__ Wd, const float* __restrict__ bd,
    float* ctxs, float* hbuf, float* hnbuf, float* h1rot, float* h2rot,
    float* smax, float* ssumg, float* ctxpart,
    float* __restrict__ out, unsigned* flagsA, unsigned* flags1) {
  extern __shared__ float dyn[];
  float* x_s  = dyn;                 // [u][65], conflict-free
  float* h_st = dyn + 512 * 65;      // [b_l][516]
  __shared__ float zp[4][64][2];
  __shared__ float p_s[64];
  __shared__ float ctx_s[64];
  __shared__ float zp1[4][64];
  __shared__ float zp2[4][64];

  const int tid = threadIdx.x;
  const int bid = blockIdx.x;
  const int g    = bid >> 5;
  const int wgid = bid & 31;
  const int u0   = wgid * 16;
  unsigned* gfA = flagsA + g * 32 * FSTR;
  unsigned* gf1 = flags1 + g * 32 * FSTR;

  // attn role mapping (tid < 512)
  const int kh  = tid & 1;
  const int b_l = (tid >> 1) & 3;
  const int col = tid >> 3;                       // 0..63
  const int zcolA = (col >> 4) * 512 + u0 + (col & 15);
  const int b_att = 4 * g + (wgid >> 3);
  const int sc = wgid & 7;

  // chaser role mapping (both roles): ct = tid mod 256
  const int ct  = tid & 255;
  const int cbl = ct & 3;                         // batch in group
  const int ccl = ct >> 2;                        // 0..63 gate-col
  const int czc = (ccl >> 4) * 512 + u0 + (ccl & 15);
  const int cb  = 4 * g + cbl;

  for (int idx = tid; idx < 64 * 512; idx += 1024) {
    int sl = idx >> 9, u = idx & 511;
    x_s[u * 65 + sl] = x[((size_t)b_att * S_ + sc * 64 + sl) * U_ + u];
  }
  float c = 0.f, hn_reg = 0.f;       // attn cell state (gate threads)
  float c1 = 0.f, c2 = 0.f;          // chaser cell states (gate threads)
  __syncthreads();

  for (int t = 0; t < T_ + 4; ++t) {
    const bool aON = (t < T_);
    const int s1 = t - 2; const bool l1 = (s1 >= 0) && (s1 < T_);
    const int s2 = t - 4; const bool l2 = (s2 >= 0) && (s2 < T_);
    float w1a = 0.f, w2a = 0.f;

    // ---- P0: attn stage h(t) (virgin rotating lines; t==0 zero) ----
    if (aON && tid < 512) {
      float4 v = make_float4(0.f, 0.f, 0.f, 0.f);
      if (t) v = ((const float4*)(hbuf + (size_t)t * 16384 + 4 * g * 512))[tid];
      *(float4*)(h_st + (tid >> 7) * 516 + (tid & 127) * 4) = v;
    }
    __syncthreads();
    // ---- P1: attn GEMV h(LDS) x RT(L2) ----
    if (aON && tid < 512) {
      const float4* H4 = (const float4*)(h_st + b_l * 516 + kh * 256);
      const float4* R4 = (const float4*)(RT + (size_t)zcolA * 512 + kh * 256);
      float acc = 0.f;
#pragma unroll 8
      for (int i = 0; i < 64; ++i) {
        float4 hv = H4[i]; float4 rv = R4[i];
        acc = fmaf(hv.x, rv.x, acc); acc = fmaf(hv.y, rv.y, acc);
        acc = fmaf(hv.z, rv.z, acc); acc = fmaf(hv.w, rv.w, acc);
      }
      zp[b_l][col][kh] = acc;
    }
    __syncthreads();
    // ---- P2: attn gates -> hn publish ----
    if (aON && tid < 64) {
      const int bb = tid >> 4, uu = tid & 15;
      const int b = 4 * g + bb, u = u0 + uu;
      const float* zy = ZY + ((size_t)b * T_ + t) * G4 + u;
      float zi = zy[0]    + zp[bb][uu][0]      + zp[bb][uu][1];
      float zf = zy[512]  + zp[bb][16 + uu][0] + zp[bb][16 + uu][1];
      float zg = zy[1024] + zp[bb][32 + uu][0] + zp[bb][32 + uu][1];
      float zo = zy[1536] + zp[bb][48 + uu][0] + zp[bb][48 + uu][1];
      float ig = 1.f / (1.f + expf(-zi));
      float fg = 1.f / (1.f + expf(-zf));
      float gg = tanhf(zg);
      float og = 1.f / (1.f + expf(-zo));
      c = fg * c + ig * gg;
      hn_reg = og * tanhf(c);
      AT_ST(&hnbuf[(size_t)t * 16384 + b * 512 + u], hn_reg);
    }
    __syncthreads();                               // BAR1 front
    if (aON && tid < 32) {
      if (tid == 0) AT_ST(&gfA[wgid * FSTR], 3u * t + 1u);
      while (!__all(AT_LD(&gfA[tid * FSTR]) >= 3u * t + 1u))
        __builtin_amdgcn_s_sleep(1);
    }
    // ---- W1 window (overlaps BAR1 poll): chaser W-dots ----
    if (l1 && tid >= 512 && tid < 768) {
      const float4* W4 = (const float4*)(W1T + (size_t)czc * 512);
      const float4* X4 = (const float4*)(ctxs + ((size_t)cb * T_ + s1) * U_);
      float a = 0.f;
#pragma unroll 8
      for (int i = 0; i < 128; ++i) {
        float4 wv = W4[i]; float4 xv = X4[i];
        a = fmaf(xv.x, wv.x, a); a = fmaf(xv.y, wv.y, a);
        a = fmaf(xv.z, wv.z, a); a = fmaf(xv.w, wv.w, a);
      }
      w1a = a;
    }
    if (l2 && tid >= 768) {
      const float4* W4 = (const float4*)(W2T + (size_t)czc * 512);
      const float4* H4 =
          (const float4*)(h1rot + (size_t)(s2 + 1) * 16384 + (size_t)cb * 512);
      float a = 0.f;
#pragma unroll 8
      for (int i = 0; i < 128; ++i) {
        float4 wv = W4[i]; float4 hv = H4[i];
        a = fmaf(hv.x, wv.x, a); a = fmaf(hv.y, wv.y, a);
        a = fmaf(hv.z, wv.z, a); a = fmaf(hv.w, wv.w, a);
      }
      w2a = a;
    }
    __syncthreads();                               // BAR1 back
    // ---- P3: attn scores ----
    if (aON && tid < 512) {
      const int wv = tid >> 6, ln = tid & 63;
      const float* hnb = hnbuf + (size_t)t * 16384 + b_att * 512;
      float hreg[8];
#pragma unroll
      for (int k = 0; k < 8; ++k) hreg[k] = hnb[ln + 64 * k];
      for (int si = 0; si < 8; ++si) {
        const int sl = wv * 8 + si;
        float a = 0.f;
#pragma unroll
        for (int k = 0; k < 8; ++k)
          a = fmaf(hreg[k], x_s[(ln + 64 * k) * 65 + sl], a);
#pragma unroll
        for (int off = 32; off; off >>= 1) a += __shfl_down(a, off);
        if (ln == 0) p_s[sl] = a;
      }
    }
    __syncthreads();
    // ---- P4: local softmax ----
    if (aON && tid < 64) {
      float v = p_s[tid];
      float m = v;
#pragma unroll
      for (int off = 32; off; off >>= 1) m = fmaxf(m, __shfl_down(m, off));
      m = __shfl(m, 0);
      float ex = expf(v - m);
      p_s[tid] = ex;
      float sm = ex;
#pragma unroll
      for (int off = 32; off; off >>= 1) sm += __shfl_down(sm, off);
      if (tid == 0) {
        AT_ST(&smax[b_att * 8 + sc], m);
        AT_ST(&ssumg[b_att * 8 + sc], sm);
      }
    }
    __syncthreads();
    // ---- P5: ctx partials ----
    if (aON && tid < 512) {
      float a = 0.f;
      const float* xr = x_s + tid * 65;
#pragma unroll 8
      for (int s = 0; s < 64; ++s) a = fmaf(p_s[s], xr[s], a);
      AT_ST(&ctxpart[((size_t)b_att * 8 + sc) * 512 + tid], a);
    }
    __syncthreads();                               // BAR2 front
    if (aON && tid < 32) {
      if (tid == 0) AT_ST(&gfA[wgid * FSTR], 3u * t + 2u);
      while (!__all(AT_LD(&gfA[tid * FSTR]) >= 3u * t + 2u))
        __builtin_amdgcn_s_sleep(1);
    }
    // ---- W2 window (overlaps BAR2 poll): chaser R-dots + zp publish ----
    if (l1 && tid >= 512 && tid < 768) {
      float a = 0.f;
      if (s1) {
        const float4* R4 = (const float4*)(R1T + (size_t)czc * 512);
        const float4* H4 =
            (const float4*)(h1rot + (size_t)s1 * 16384 + (size_t)cb * 512);
#pragma unroll 8
        for (int i = 0; i < 128; ++i) {
          float4 rv = R4[i]; float4 hv = H4[i];
          a = fmaf(hv.x, rv.x, a); a = fmaf(hv.y, rv.y, a);
          a = fmaf(hv.z, rv.z, a); a = fmaf(hv.w, rv.w, a);
        }
      }
      zp1[cbl][ccl] = w1a + a;
    }
    if (l2 && tid >= 768) {
      float a = 0.f;
      if (s2) {
        const float4* R4 = (const float4*)(R2T + (size_t)czc * 512);
        const float4* H4 =
            (const float4*)(h2rot + (size_t)s2 * 16384 + (size_t)cb * 512);
#pragma unroll 8
        for (int i = 0; i < 128; ++i) {
          float4 rv = R4[i]; float4 hv = H4[i];
          a = fmaf(hv.x, rv.x, a); a = fmaf(hv.y, rv.y, a);
          a = fmaf(hv.z, rv.z, a); a = fmaf(hv.w, rv.w, a);
        }
      }
      zp2[cbl][ccl] = w2a + a;
    }
    __syncthreads();                               // BAR2 back
    // ---- P6: attn combine ----
    if (aON && tid < 512) {
      const int j = tid & 7;
      const int pair = tid >> 3;
      const int bb = pair >> 4, uu = pair & 15;
      const int b = 4 * g + bb, u = u0 + uu;
      float lm = AT_LD(&smax[b * 8 + j]);
      float ss = AT_LD(&ssumg[b * 8 + j]);
      float cp = AT_LD(&ctxpart[((size_t)b * 8 + j) * 512 + u]);
      float gm = lm;
#pragma unroll
      for (int off = 1; off < 8; off <<= 1)
        gm = fmaxf(gm, __shfl_xor(gm, off));
      float w = expf(lm - gm);
      float st = ss * w, cs = cp * w;
#pragma unroll
      for (int off = 1; off < 8; off <<= 1) {
        st += __shfl_xor(st, off);
        cs += __shfl_xor(cs, off);
      }
      if (j == 0) ctx_s[pair] = cs / st;
    }
    __syncthreads();
    // ---- P7: publishes (attn h/ctxs, lstm1 h1, lstm2 h2) ----
    if (aON && tid < 64) {
      const int bb = tid >> 4, uu = tid & 15;
      const int b = 4 * g + bb, u = u0 + uu;
      float ctxv = ctx_s[tid];
      c += ctxv;
      float hcar = hn_reg + ctxv;
      AT_ST(&hbuf[(size_t)(t + 1) * 16384 + b * 512 + u], hcar);
      AT_ST(&ctxs[((size_t)b * T_ + t) * U_ + u], ctxv);
    }
    if (l1 && tid >= 512 && tid < 576) {
      const int cc = tid - 512;
      const int bb = cc >> 4, uu = cc & 15;
      const int b = 4 * g + bb, u = u0 + uu;
      float zi = b1[u]        + zp1[bb][uu];
      float zf = b1[512 + u]  + zp1[bb][16 + uu];
      float zg = b1[1024 + u] + zp1[bb][32 + uu];
      float zo = b1[1536 + u] + zp1[bb][48 + uu];
      float ig = 1.f / (1.f + expf(-zi));
      float fg = 1.f / (1.f + expf(-zf));
      float gg = tanhf(zg);
      float og = 1.f / (1.f + expf(-zo));
      c1 = fg * c1 + ig * gg;
      float hv = og * tanhf(c1);
      AT_ST(&h1rot[(size_t)(s1 + 1) * 16384 + (size_t)b * 512 + u], hv);
    }
    if (l2 && tid >= 768 && tid < 832) {
      const int cc = tid - 768;
      const int bb = cc >> 4, uu = cc & 15;
      const int b = 4 * g + bb, u = u0 + uu;
      float zi = b2[u]        + zp2[bb][uu];
      float zf = b2[512 + u]  + zp2[bb][16 + uu];
      float zg = b2[1024 + u] + zp2[bb][32 + uu];
      float zo = b2[1536 + u] + zp2[bb][48 + uu];
      float ig = 1.f / (1.f + expf(-zi));
      float fg = 1.f / (1.f + expf(-zf));
      float gg = tanhf(zg);
      float og = 1.f / (1.f + expf(-zo));
      c2 = fg * c2 + ig * gg;
      float hv = og * tanhf(c2);
      AT_ST(&h2rot[(size_t)(s2 + 1) * 16384 + (size_t)b * 512 + u], hv);
    }
    __syncthreads();                               // BAR3 front
    if (aON && tid < 32) {
      if (tid == 0) AT_ST(&gfA[wgid * FSTR], 3u * t + 3u);
      while (!__all(AT_LD(&gfA[tid * FSTR]) >= 3u * t + 3u))
        __builtin_amdgcn_s_sleep(1);
    }
    __syncthreads();                               // BAR3 back
    // ---- drain iterations: cohort bar on FLG_1 sustains the chain ----
    if (t >= T_) {
      if (tid < 32) {
        unsigned dseq = (unsigned)(t - T_ + 1);
        if (tid == 0) AT_ST(&gf1[wgid * FSTR], dseq);
        while (!__all(AT_LD(&gf1[tid * FSTR]) >= dseq))
          __builtin_amdgcn_s_sleep(1);
      }
      __syncthreads();
    }
  }

  // ---- folded decoder: wgid 0 of each cohort, waves 8-11, final_k math ----
  if (wgid == 0 && tid >= 512 && tid < 768) {
    const int cc = tid - 512;
    const int b = 4 * g + (cc >> 6);
    const int v = cc & 63;
    const float* hT = h2rot + (size_t)T_ * 16384 + (size_t)b * 512;
    float acc = (v < V_) ? bd[v] : -INFINITY;
    if (v < V_) {
      for (int k = 0; k < U_; ++k)
        acc = fmaf(hT[k], Wd[(size_t)k * V_ + v], acc);
    }
    float m = acc;
#pragma unroll
    for (int off = 32; off; off >>= 1) m = fmaxf(m, __shfl_down(m, off));
    m = __shfl(m, 0);
    float e = (v < V_) ? expf(acc - m) : 0.f;
    float s = e;
#pragma unroll
    for (int off = 32; off; off >>= 1) s += __shfl_down(s, off);
    s = __shfl(s, 0);
    if (v < V_) out[(size_t)b * V_ + v] = e / s;
  }
}

extern "C" void kernel_launch(void* const* d_in, const int* in_sizes, int n_in,
                              void* d_out, int out_size, void* d_ws, size_t ws_size,
                              hipStream_t stream) {
  const float* x   = (const float*)d_in[0];
  const float* y   = (const float*)d_in[1];
  const float* W_a = (const float*)d_in[2];
  const float* R_a = (const float*)d_in[3];
  const float* b_a = (const float*)d_in[4];
  const float* W1  = (const float*)d_in[5];
  const float* R1  = (const float*)d_in[6];
  const float* b1  = (const float*)d_in[7];
  const float* W2  = (const float*)d_in[8];
  const float* R2  = (const float*)d_in[9];
  const float* b2  = (const float*)d_in[10];
  const float* Wd  = (const float*)d_in[11];
  const float* bd  = (const float*)d_in[12];
  float* out = (float*)d_out;

  float* ZBUF  = (float*)d_ws;                   // 8388608
  float* CTXS  = ZBUF + (size_t)8388608;         // 2097152
  float* RT    = CTXS + (size_t)2097152;         // 1048576
  float* W1T   = RT + (size_t)1048576;           // 1048576
  float* R1T   = W1T + (size_t)1048576;          // 1048576
  float* W2T   = R1T + (size_t)1048576;          // 1048576
  float* R2T   = W2T + (size_t)1048576;          // 1048576
  float* HROT  = R2T + (size_t)1048576;          // 129*16384 = 2113536
  float* HNROT = HROT + (size_t)2113536;         // 128*16384 = 2097152
  float* H1ROT = HNROT + (size_t)2097152;        // 2113536
  float* H2ROT = H1ROT + (size_t)2113536;        // 2113536
  float* SMAX  = H2ROT + (size_t)2113536;        // 256
  float* SSUM  = SMAX + 256;                     // 256
  float* CTXP  = SSUM + 256;                     // 131072
  unsigned* BAR = (unsigned*)(CTXP + 131072);

  const int REGION = 8 * 32 * FSTR;              // 8192 u32 per flag set
  unsigned* FLG_A = BAR;
  unsigned* FLG_1 = BAR + REGION;

  const int mega_lds = (512 * 65 + 4 * 516) * 4;    // 141376 B
  hipFuncSetAttribute((const void*)mega,
                      hipFuncAttributeMaxDynamicSharedMemorySize, mega_lds);

  dim3 ggrid(2, 512);
  hipMemsetAsync(BAR, 0, 2 * REGION * 4, stream);

  gemm_k512<<<ggrid, 256, 0, stream>>>(y, W_a, b_a, ZBUF);
  transpose_R<<<dim3(32, 8), 256, 0, stream>>>(R_a, RT);
  transpose_R<<<dim3(32, 8), 256, 0, stream>>>(W1, W1T);
  transpose_R<<<dim3(32, 8), 256, 0, stream>>>(R1, R1T);
  transpose_R<<<dim3(32, 8), 256, 0, stream>>>(W2, W2T);
  transpose_R<<<dim3(32, 8), 256, 0, stream>>>(R2, R2T);
  mega<<<256, 1024, mega_lds, stream>>>(x, ZBUF, RT, W1T, R1T, b1,
                                        W2T, R2T, b2, Wd, bd,
                                        CTXS, HROT, HNROT, H1ROT, H2ROT,
                                        SMAX, SSUM, CTXP, out, FLG_A, FLG_1);
}

// Round 10
// 4063.200 us; speedup vs baseline: 2.7411x; 2.7411x over previous
//
#include <hip/hip_runtime.h>
#include <math.h>

// Speller FINAL == round 13 (verified 3983/4037us, reproduced twice).
//   Ledger: v8 redundancy ✗, v9 2xWG/CU ✗ (spin collapse), v10 fusion ✗,
//   v11 trim flat (in barrier shadow), v12 narrow groups ✗ (L2 stream),
//   v14 corrected fusion ✗ (stacked exchange floors), v16 mega-block ✗
//   (block-wide __syncthreads puts chasers ON the critical path; weight
//   streams exceed L2 -> ~83us/iter). Structure is forced: R (4MB) ->
//   32-WG cooperative groups -> per-step all-to-all; data deps -> 3
//   exchanges/step attn, 1/step lstm. Floor: 640 exchanges x ~4us IF$ RTT
//   + in-shadow compute + 255us GEMM ≈ 3.95ms. Sync-latency roofline:
//   HBM 2%, VALU 13%, MfmaUtil 0, occupancy 24%.

#define U_   512
#define S_   512
#define T_   128
#define B_   32
#define G4   2048
#define V_   46
#define NWG  256
#define FSTR 32            // flag stride in u32 = 128 B

#define AT_LD(p)     __hip_atomic_load((p), __ATOMIC_RELAXED, __HIP_MEMORY_SCOPE_AGENT)
#define AT_ST(p, v)  __hip_atomic_store((p), (v), __ATOMIC_RELAXED, __HIP_MEMORY_SCOPE_AGENT)

// 1-hop barrier over the 32 WGs of this group. gflags = 32 padded slots.
__device__ __forceinline__ void group_bar(unsigned* gflags, unsigned seq) {
  __syncthreads();   // all waves' stores drained (vmcnt) before arrival
  const int tid = threadIdx.x;
  if (tid < 32) {
    if (tid == 0)
      AT_ST(&gflags[(blockIdx.x & 31) * FSTR], seq);
    while (!__all(AT_LD(&gflags[tid * FSTR]) >= seq))
      __builtin_amdgcn_s_sleep(1);
  }
  __syncthreads();
}

// ---------------- GEMM: Z[M,2048] = A[M,512] @ W[512,2048] + b ----------------
__global__ __launch_bounds__(256) void gemm_k512(
    const float* __restrict__ A, const float* __restrict__ W,
    const float* __restrict__ b, float* __restrict__ Z) {
  const int tid = threadIdx.x;
  const int j = blockIdx.x * 1024 + tid * 4;
  const int i0 = blockIdx.y * 8;
  float4 bj = *(const float4*)(b + j);
  float4 acc[8];
#pragma unroll
  for (int r = 0; r < 8; ++r) acc[r] = bj;
  const float* Arow = A + (size_t)i0 * U_;
  for (int k = 0; k < U_; ++k) {
    float4 w = *(const float4*)(W + (size_t)k * G4 + j);
#pragma unroll
    for (int r = 0; r < 8; ++r) {
      float a = Arow[(size_t)r * U_ + k];
      acc[r].x = fmaf(a, w.x, acc[r].x);
      acc[r].y = fmaf(a, w.y, acc[r].y);
      acc[r].z = fmaf(a, w.z, acc[r].z);
      acc[r].w = fmaf(a, w.w, acc[r].w);
    }
  }
#pragma unroll
  for (int r = 0; r < 8; ++r)
    *(float4*)(Z + (size_t)(i0 + r) * G4 + j) = acc[r];
}

// ---------------- transpose R[512][2048] -> RT[2048][512] ----------------
__global__ __launch_bounds__(256) void transpose_R(
    const float* __restrict__ R, float* __restrict__ RT) {
  __shared__ float tile[64][65];
  const int c0 = blockIdx.x * 64, k0 = blockIdx.y * 64;
  const int tc = threadIdx.x & 63, tr = threadIdx.x >> 6;
  for (int r = tr; r < 64; r += 4)
    tile[r][tc] = R[(size_t)(k0 + r) * G4 + c0 + tc];
  __syncthreads();
  for (int r = tr; r < 64; r += 4)
    RT[(size_t)(c0 + r) * 512 + k0 + tc] = tile[tc][r];
}

// ---------------- attention LSTM: 8 groups x 32 WGs, 4 batches/group ------
// dyn LDS: x_s [512][65] + h_st [4][516]  = 141376 B
// hbuf: rotating [T+1][32][512] (slot 0 unused: t==0 zero-fills in-kernel)
// hnbuf: rotating [T][32][512]
__global__ __launch_bounds__(512) void attn_coop(
    const float* __restrict__ x, const float* __restrict__ ZY,
    const float* __restrict__ RT, float* __restrict__ ctxs,
    float* hbuf, float* hnbuf, float* smax, float* ssumg,
    float* ctxpart, unsigned* flags) {
  extern __shared__ float dyn[];
  float* x_s  = dyn;                 // [u][65], conflict-free
  float* h_st = dyn + 512 * 65;      // [b_l][516]
  __shared__ float zp[4][64][2];
  __shared__ float p_s[64];
  __shared__ float ctx_s[64];

  const int tid = threadIdx.x;
  const int bid = blockIdx.x;
  const int g    = bid >> 5;
  const int wgid = bid & 31;
  const int u0   = wgid * 16;
  // GEMV role mapping: 64 cols x 4 batches x 2 k-halves
  const int kh  = tid & 1;
  const int b_l = (tid >> 1) & 3;
  const int col = tid >> 3;                       // 0..63
  const int zcol = (col >> 4) * 512 + u0 + (col & 15);
  // attention role mapping
  const int b_att = 4 * g + (wgid >> 3);
  const int sc = wgid & 7;
  unsigned* gflags = flags + g * 32 * FSTR;

  for (int idx = tid; idx < 64 * 512; idx += 512) {
    int sl = idx >> 9, u = idx & 511;
    x_s[u * 65 + sl] = x[((size_t)b_att * S_ + sc * 64 + sl) * U_ + u];
  }
  float c = 0.f, hn_reg = 0.f;
  unsigned seq = 0;
  __syncthreads();

  for (int t = 0; t < T_; ++t) {
    // ---- stage h slot t (cached float4 burst: virgin lines -> IF$) ----
    {
      float4 v = make_float4(0.f, 0.f, 0.f, 0.f);
      if (t) {
        const float4* hb4 =
            (const float4*)(hbuf + (size_t)t * 16384 + 4 * g * 512);
        v = hb4[tid];
      }
      *(float4*)(h_st + (tid >> 7) * 516 + (tid & 127) * 4) = v;
    }
    __syncthreads();
    // ---- GEMV: z-partial from h(LDS) x RT(L2) ----
    {
      const float4* H4 = (const float4*)(h_st + b_l * 516 + kh * 256);
      const float4* R4 = (const float4*)(RT + (size_t)zcol * 512 + kh * 256);
      float acc = 0.f;
#pragma unroll 8
      for (int i = 0; i < 64; ++i) {
        float4 hv = H4[i];
        float4 rv = R4[i];
        acc = fmaf(hv.x, rv.x, acc); acc = fmaf(hv.y, rv.y, acc);
        acc = fmaf(hv.z, rv.z, acc); acc = fmaf(hv.w, rv.w, acc);
      }
      zp[b_l][col][kh] = acc;
    }
    __syncthreads();
    if (tid < 64) {
      const int bb = tid >> 4, uu = tid & 15;
      const int b = 4 * g + bb, u = u0 + uu;
      const float* zy = ZY + ((size_t)b * T_ + t) * G4 + u;
      float zi = zy[0]    + zp[bb][uu][0]      + zp[bb][uu][1];
      float zf = zy[512]  + zp[bb][16 + uu][0] + zp[bb][16 + uu][1];
      float zg = zy[1024] + zp[bb][32 + uu][0] + zp[bb][32 + uu][1];
      float zo = zy[1536] + zp[bb][48 + uu][0] + zp[bb][48 + uu][1];
      float ig = 1.f / (1.f + expf(-zi));
      float fg = 1.f / (1.f + expf(-zf));
      float gg = tanhf(zg);
      float og = 1.f / (1.f + expf(-zo));
      c = fg * c + ig * gg;
      hn_reg = og * tanhf(c);
      AT_ST(&hnbuf[(size_t)t * 16384 + b * 512 + u], hn_reg);
    }
    group_bar(gflags, ++seq);

    // ---- scores (hn in 8 regs, read once from rotating hnbuf slot),
    //      local softmax, ctx partials ----
    {
      const int wv = tid >> 6, ln = tid & 63;
      const float* hnb = hnbuf + (size_t)t * 16384 + b_att * 512;
      float hreg[8];
#pragma unroll
      for (int k = 0; k < 8; ++k) hreg[k] = hnb[ln + 64 * k];
      for (int si = 0; si < 8; ++si) {
        const int sl = wv * 8 + si;
        float a = 0.f;
#pragma unroll
        for (int k = 0; k < 8; ++k)
          a = fmaf(hreg[k], x_s[(ln + 64 * k) * 65 + sl], a);
#pragma unroll
        for (int off = 32; off; off >>= 1) a += __shfl_down(a, off);
        if (ln == 0) p_s[sl] = a;
      }
    }
    __syncthreads();
    if (tid < 64) {
      float v = p_s[tid];
      float m = v;
#pragma unroll
      for (int off = 32; off; off >>= 1) m = fmaxf(m, __shfl_down(m, off));
      m = __shfl(m, 0);
      float ex = expf(v - m);
      p_s[tid] = ex;
      float sm = ex;
#pragma unroll
      for (int off = 32; off; off >>= 1) sm += __shfl_down(sm, off);
      if (tid == 0) {
        AT_ST(&smax[b_att * 8 + sc], m);
        AT_ST(&ssumg[b_att * 8 + sc], sm);
      }
    }
    __syncthreads();
    {
      float a = 0.f;
      const float* xr = x_s + tid * 65;
#pragma unroll 8
      for (int s = 0; s < 64; ++s) a = fmaf(p_s[s], xr[s], a);
      AT_ST(&ctxpart[((size_t)b_att * 8 + sc) * 512 + tid], a);
    }
    group_bar(gflags, ++seq);

    // ---- combine slices (parallel over 512 thr: pair x j, sc1 gathers) ----
    {
      const int j = tid & 7;
      const int pair = tid >> 3;            // 0..63 == gates-thread index
      const int bb = pair >> 4, uu = pair & 15;
      const int b = 4 * g + bb, u = u0 + uu;
      float lm = AT_LD(&smax[b * 8 + j]);
      float ss = AT_LD(&ssumg[b * 8 + j]);
      float cp = AT_LD(&ctxpart[((size_t)b * 8 + j) * 512 + u]);
      float gm = lm;
#pragma unroll
      for (int off = 1; off < 8; off <<= 1)
        gm = fmaxf(gm, __shfl_xor(gm, off));
      float w = expf(lm - gm);
      float st = ss * w, cs = cp * w;
#pragma unroll
      for (int off = 1; off < 8; off <<= 1) {
        st += __shfl_xor(st, off);
        cs += __shfl_xor(cs, off);
      }
      if (j == 0) ctx_s[pair] = cs / st;
    }
    __syncthreads();
    if (tid < 64) {
      const int bb = tid >> 4, uu = tid & 15;
      const int b = 4 * g + bb, u = u0 + uu;
      float ctxv = ctx_s[tid];
      c += ctxv;
      float hcar = hn_reg + ctxv;
      AT_ST(&hbuf[(size_t)(t + 1) * 16384 + b * 512 + u], hcar);
      ctxs[((size_t)b * T_ + t) * U_ + u] = ctxv;
    }
    group_bar(gflags, ++seq);
  }
}

// ---------------- plain LSTM: 8 groups x 32 WGs ----------------
// dyn LDS: R_s [64][516] + h_st [4][516] = 140352 B; hbuf rotating
// (slot 0 unused: t==0 zero-fills in-kernel)
// If Wd != nullptr: decoder folded into epilogue (bit-identical to final_k).
__global__ __launch_bounds__(512) void lstm_coop(
    const float* __restrict__ Zin, const float* __restrict__ R,
    float* __restrict__ seq_out, float* hbuf, unsigned* flags,
    const float* __restrict__ Wd, const float* __restrict__ bd,
    float* __restrict__ out) {
  extern __shared__ float dyn[];
  float* R_s  = dyn;                 // [col][516]
  float* h_st = dyn + 64 * 516;      // [b_l][516]
  __shared__ float zp[4][64][2];
  const int tid = threadIdx.x;
  const int bid = blockIdx.x;
  const int g    = bid >> 5;
  const int wgid = bid & 31;
  const int u0   = wgid * 16;
  const int kh  = tid & 1;
  const int b_l = (tid >> 1) & 3;
  const int col = tid >> 3;
  unsigned* gflags = flags + g * 32 * FSTR;

  // one-time R slice -> LDS (transposed to [col][k])
  for (int idx = tid; idx < 64 * 512; idx += 512) {
    int cc = idx & 63, kk = idx >> 6;
    R_s[cc * 516 + kk] = R[(size_t)kk * G4 + (cc >> 4) * 512 + u0 + (cc & 15)];
  }
  float c = 0.f;
  unsigned seq = 0;
  __syncthreads();

  for (int t = 0; t < T_; ++t) {
    {
      float4 v = make_float4(0.f, 0.f, 0.f, 0.f);
      if (t) {
        const float4* hb4 =
            (const float4*)(hbuf + (size_t)t * 16384 + 4 * g * 512);
        v = hb4[tid];
      }
      *(float4*)(h_st + (tid >> 7) * 516 + (tid & 127) * 4) = v;
    }
    __syncthreads();
    {
      const float4* H4 = (const float4*)(h_st + b_l * 516 + kh * 256);
      const float4* R4 = (const float4*)(R_s + col * 516 + kh * 256);
      float acc = 0.f;
#pragma unroll 8
      for (int i = 0; i < 64; ++i) {
        float4 hv = H4[i];
        float4 rv = R4[i];
        acc = fmaf(hv.x, rv.x, acc); acc = fmaf(hv.y, rv.y, acc);
        acc = fmaf(hv.z, rv.z, acc); acc = fmaf(hv.w, rv.w, acc);
      }
      zp[b_l][col][kh] = acc;
    }
    __syncthreads();
    if (tid < 64) {
      const int bb = tid >> 4, uu = tid & 15;
      const int b = 4 * g + bb, u = u0 + uu;
      const float* zy = Zin + ((size_t)b * T_ + t) * G4 + u;
      float zi = zy[0]    + zp[bb][uu][0]      + zp[bb][uu][1];
      float zf = zy[512]  + zp[bb][16 + uu][0] + zp[bb][16 + uu][1];
      float zg = zy[1024] + zp[bb][32 + uu][0] + zp[bb][32 + uu][1];
      float zo = zy[1536] + zp[bb][48 + uu][0] + zp[bb][48 + uu][1];
      float ig = 1.f / (1.f + expf(-zi));
      float fg = 1.f / (1.f + expf(-zf));
      float gg = tanhf(zg);
      float og = 1.f / (1.f + expf(-zo));
      c = fg * c + ig * gg;
      float hv2 = og * tanhf(c);
      AT_ST(&hbuf[(size_t)(t + 1) * 16384 + b * 512 + u], hv2);
      if (seq_out) seq_out[((size_t)b * T_ + t) * U_ + u] = hv2;
    }
    group_bar(gflags, ++seq);
  }

  // ---- folded decoder (lstm2 only): one wave per batch, wgid 0 of each
  //      group; bit-identical accumulation/reduction order to final_k ----
  if (Wd && wgid == 0 && tid < 256) {
    const int b = 4 * g + (tid >> 6);
    const int v = tid & 63;
    const float* hT = hbuf + (size_t)T_ * 16384 + (size_t)b * 512;
    float acc = (v < V_) ? bd[v] : -INFINITY;
    if (v < V_) {
      for (int k = 0; k < U_; ++k)
        acc = fmaf(hT[k], Wd[(size_t)k * V_ + v], acc);
    }
    float m = acc;
#pragma unroll
    for (int off = 32; off; off >>= 1) m = fmaxf(m, __shfl_down(m, off));
    m = __shfl(m, 0);
    float e = (v < V_) ? expf(acc - m) : 0.f;
    float s = e;
#pragma unroll
    for (int off = 32; off; off >>= 1) s += __shfl_down(s, off);
    s = __shfl(s, 0);
    if (v < V_) out[(size_t)b * V_ + v] = e / s;
  }
}

extern "C" void kernel_launch(void* const* d_in, const int* in_sizes, int n_in,
                              void* d_out, int out_size, void* d_ws, size_t ws_size,
                              hipStream_t stream) {
  const float* x   = (const float*)d_in[0];
  const float* y   = (const float*)d_in[1];
  const float* W_a = (const float*)d_in[2];
  const float* R_a = (const float*)d_in[3];
  const float* b_a = (const float*)d_in[4];
  const float* W1  = (const float*)d_in[5];
  const float* R1  = (const float*)d_in[6];
  const float* b1  = (const float*)d_in[7];
  const float* W2  = (const float*)d_in[8];
  const float* R2  = (const float*)d_in[9];
  const float* b2  = (const float*)d_in[10];
  const float* Wd  = (const float*)d_in[11];
  const float* bd  = (const float*)d_in[12];
  float* out = (float*)d_out;

  float* ZBUF  = (float*)d_ws;                   // 8388608 f
  float* SEQ   = ZBUF + (size_t)8388608;         // 2097152 f
  float* RT    = SEQ + (size_t)2097152;          // 1048576 f
  float* HROT  = RT + (size_t)1048576;           // 129*16384 = 2113536 f
  float* HNROT = HROT + (size_t)2113536;         // 128*16384 = 2097152 f
  float* SMAX  = HNROT + (size_t)2097152;        // 256
  float* SSUM  = SMAX + 256;                     // 256
  float* CTXP  = SSUM + 256;                     // 131072
  float* HT    = CTXP + 131072;                  // 16384 (unused, kept for layout)
  unsigned* BAR = (unsigned*)(HT + 16384);

  // per kernel-instance: 8 groups x 32 flags x FSTR
  const int REGION = 8 * 32 * FSTR;              // 8192 u32
  unsigned* FLG_A = BAR;
  unsigned* FLG_1 = BAR + REGION;
  unsigned* FLG_2 = BAR + 2 * REGION;

  const int attn_lds = (512 * 65 + 4 * 516) * 4;    // 141376 B
  const int lstm_lds = (64 * 516 + 4 * 516) * 4;    // 140352 B
  hipFuncSetAttribute((const void*)attn_coop,
                      hipFuncAttributeMaxDynamicSharedMemorySize, attn_lds);
  hipFuncSetAttribute((const void*)lstm_coop,
                      hipFuncAttributeMaxDynamicSharedMemorySize, lstm_lds);

  dim3 ggrid(2, 512);
  hipMemsetAsync(BAR, 0, 3 * REGION * 4, stream);

  gemm_k512<<<ggrid, 256, 0, stream>>>(y, W_a, b_a, ZBUF);
  transpose_R<<<dim3(32, 8), 256, 0, stream>>>(R_a, RT);
  attn_coop<<<NWG, 512, attn_lds, stream>>>(x, ZBUF, RT, SEQ, HROT, HNROT,
                                            SMAX, SSUM, CTXP, FLG_A);
  gemm_k512<<<ggrid, 256, 0, stream>>>(SEQ, W1, b1, ZBUF);
  lstm_coop<<<NWG, 512, lstm_lds, stream>>>(ZBUF, R1, SEQ, HROT, FLG_1,
                                            nullptr, nullptr, nullptr);
  gemm_k512<<<ggrid, 256, 0, stream>>>(SEQ, W2, b2, ZBUF);
  lstm_coop<<<NWG, 512, lstm_lds, stream>>>(ZBUF, R2, nullptr, HROT, FLG_2,
                                            Wd, bd, out);
}